// Round 1
// baseline (125.921 us; speedup 1.0000x reference)
//
#include <hip/hip_runtime.h>

#define VOL   (16 * 16 * 16 * 16)   // 65536 sites
#define NSC   12                     // NS*NC
#define DIAG  4.1f

// complex mul-accumulate of a float4 chunk: (kr + i ki) * (vr + i vi)
#define CMADD(kr, ki, vr, vi)                                              \
    sr += kr.x * vr.x - ki.x * vi.x;  si += kr.x * vi.x + ki.x * vr.x;     \
    sr += kr.y * vr.y - ki.y * vi.y;  si += kr.y * vi.y + ki.y * vr.y;     \
    sr += kr.z * vr.z - ki.z * vi.z;  si += kr.z * vi.z + ki.z * vr.z;     \
    sr += kr.w * vr.w - ki.w * vi.w;  si += kr.w * vi.w + ki.w * vr.w;

__global__ __launch_bounds__(256) void dslash_kernel(
    const float* __restrict__ psi_re, const float* __restrict__ psi_im,
    const float* __restrict__ Kf_re,  const float* __restrict__ Kf_im,
    const float* __restrict__ Kb_re,  const float* __restrict__ Kb_im,
    float* __restrict__ out_re,       float* __restrict__ out_im)
{
    const int tid = blockIdx.x * blockDim.x + threadIdx.x;
    if (tid >= VOL * NSC) return;

    const int site = tid / NSC;       // compiler -> magic mul
    const int i    = tid - site * NSC;

    const int x = site        & 15;
    const int y = (site >> 4) & 15;
    const int z = (site >> 8) & 15;
    const int t = (site >> 12) & 15;

    float acc_re = DIAG * psi_re[site * NSC + i];
    float acc_im = DIAG * psi_im[site * NSC + i];

    const int coords [4] = {t, z, y, x};
    const int strides[4] = {4096, 256, 16, 1};

    #pragma unroll
    for (int mu = 0; mu < 4; ++mu) {
        const int c    = coords[mu];
        const int st   = strides[mu];
        const int base = site - c * st;
        const int sf   = base + ((c + 1)  & 15) * st;   // roll(-1): x+1
        const int sb   = base + ((c + 15) & 15) * st;   // roll(+1): x-1

        // Row i of each 12x12 matrix: 12 floats, 48B, 16B-aligned.
        const int koff = (mu * VOL + site) * 144 + i * 12;
        const float4* kfr = (const float4*)(Kf_re + koff);
        const float4* kfi = (const float4*)(Kf_im + koff);
        const float4* kbr = (const float4*)(Kb_re + koff);
        const float4* kbi = (const float4*)(Kb_im + koff);

        const float4* pfr = (const float4*)(psi_re + sf * NSC);
        const float4* pfi = (const float4*)(psi_im + sf * NSC);
        const float4* pbr = (const float4*)(psi_re + sb * NSC);
        const float4* pbi = (const float4*)(psi_im + sb * NSC);

        float sr = 0.f, si = 0.f;
        #pragma unroll
        for (int q = 0; q < 3; ++q) {
            const float4 a  = kfr[q], b  = kfi[q];
            const float4 vr = pfr[q], vi = pfi[q];
            CMADD(a, b, vr, vi);
            const float4 c4 = kbr[q], d4 = kbi[q];
            const float4 wr = pbr[q], wi = pbi[q];
            CMADD(c4, d4, wr, wi);
        }
        acc_re -= 0.5f * sr;
        acc_im -= 0.5f * si;
    }

    out_re[tid] = acc_re;
    out_im[tid] = acc_im;
}

extern "C" void kernel_launch(void* const* d_in, const int* in_sizes, int n_in,
                              void* d_out, int out_size, void* d_ws, size_t ws_size,
                              hipStream_t stream) {
    const float* psi_re = (const float*)d_in[0];
    const float* psi_im = (const float*)d_in[1];
    const float* Kf_re  = (const float*)d_in[2];
    const float* Kf_im  = (const float*)d_in[3];
    const float* Kb_re  = (const float*)d_in[4];
    const float* Kb_im  = (const float*)d_in[5];

    float* out_re = (float*)d_out;
    float* out_im = (float*)d_out + (size_t)VOL * NSC;

    const int total  = VOL * NSC;           // 786432 threads
    const int block  = 256;
    const int grid   = (total + block - 1) / block;  // 3072 blocks

    dslash_kernel<<<grid, block, 0, stream>>>(psi_re, psi_im,
                                              Kf_re, Kf_im, Kb_re, Kb_im,
                                              out_re, out_im);
}

// Round 3
// 114.725 us; speedup vs baseline: 1.0976x; 1.0976x over previous
//
#include <hip/hip_runtime.h>

#define VOL   65536                 // 16^4 sites
#define NSC   12                    // NS*NC
#define DIAG  4.1f
#define SPB   16                    // sites per block
#define THREADS (SPB * NSC)         // 192 threads = 3 waves
#define MATF  (SPB * 144)           // 2304 floats per staged matrix (9216 B)

// complex mul-accumulate of a float4 chunk: (kr + i ki) * (vr + i vi)
#define CMADD(kr, ki, vr, vi)                                              \
    sr += kr.x * vr.x - ki.x * vi.x;  si += kr.x * vi.x + ki.x * vr.x;     \
    sr += kr.y * vr.y - ki.y * vi.y;  si += kr.y * vi.y + ki.y * vr.y;     \
    sr += kr.z * vr.z - ki.z * vi.z;  si += kr.z * vi.z + ki.z * vr.z;     \
    sr += kr.w * vr.w - ki.w * vi.w;  si += kr.w * vi.w + ki.w * vr.w;

// async global -> LDS, 16 bytes per lane, fully coalesced
__device__ __forceinline__ void g2lds16(const float* g, float* l) {
    __builtin_amdgcn_global_load_lds(
        (const __attribute__((address_space(1))) unsigned int*)g,
        (__attribute__((address_space(3))) unsigned int*)l,
        16, 0, 0);
}

__global__ __launch_bounds__(THREADS) void dslash_kernel(
    const float* __restrict__ psi_re, const float* __restrict__ psi_im,
    const float* __restrict__ Kf_re,  const float* __restrict__ Kf_im,
    const float* __restrict__ Kb_re,  const float* __restrict__ Kb_im,
    float* __restrict__ out_re,       float* __restrict__ out_im)
{
    __shared__ float lds[4 * MATF];   // 36 KB: Kf_re | Kf_im | Kb_re | Kb_im

    const int j  = threadIdx.x;       // 0..191 == local row id
    const int w  = j >> 6;            // wave 0..2
    const int l  = j & 63;            // lane
    const int site0 = blockIdx.x * SPB;
    const int sl = j / NSC;           // local site 0..15
    const int i  = j - sl * NSC;      // row within 12x12
    const int site = site0 + sl;

    const int x = site        & 15;
    const int y = (site >> 4) & 15;
    const int z = (site >> 8) & 15;
    const int t = (site >> 12) & 15;
    const int coords [4] = {t, z, y, x};
    const int strides[4] = {4096, 256, 16, 1};

    float acc_re = DIAG * psi_re[site * NSC + i];
    float acc_im = DIAG * psi_im[site * NSC + i];

    const float* __restrict__ Ks[4] = {Kf_re, Kf_im, Kb_re, Kb_im};

    for (int mu = 0; mu < 4; ++mu) {
        // ---- stage 4 matrices x 16 sites, fully coalesced, async ----
        const size_t gbase = ((size_t)mu * VOL + (size_t)site0) * 144;
        #pragma unroll
        for (int m = 0; m < 4; ++m) {
            const float* src = Ks[m] + gbase;
            #pragma unroll
            for (int jj = 0; jj < 3; ++jj) {
                const int c = jj * 3 + w;             // chunk 0..8 (256 floats)
                g2lds16(src + c * 256 + l * 4, &lds[m * MATF + c * 256 + l * 4]);
            }
        }
        __syncthreads();   // compiler drains vmcnt before s_barrier

        const int cc = coords[mu], st = strides[mu];
        const int base = site - cc * st;
        const int sf = base + ((cc + 1)  & 15) * st;  // roll(-1)
        const int sb = base + ((cc + 15) & 15) * st;  // roll(+1)

        const float4* kfr = (const float4*)&lds[0 * MATF + j * 12];
        const float4* kfi = (const float4*)&lds[1 * MATF + j * 12];
        const float4* kbr = (const float4*)&lds[2 * MATF + j * 12];
        const float4* kbi = (const float4*)&lds[3 * MATF + j * 12];

        const float4* pfr = (const float4*)(psi_re + sf * NSC);
        const float4* pfi = (const float4*)(psi_im + sf * NSC);
        const float4* pbr = (const float4*)(psi_re + sb * NSC);
        const float4* pbi = (const float4*)(psi_im + sb * NSC);

        float sr = 0.f, si = 0.f;
        #pragma unroll
        for (int q = 0; q < 3; ++q) {
            const float4 a  = kfr[q], b  = kfi[q];
            const float4 vr = pfr[q], vi = pfi[q];
            CMADD(a, b, vr, vi);
            const float4 c4 = kbr[q], d4 = kbi[q];
            const float4 wr = pbr[q], wi = pbi[q];
            CMADD(c4, d4, wr, wi);
        }
        acc_re -= 0.5f * sr;
        acc_im -= 0.5f * si;
        __syncthreads();   // before next mu overwrites LDS
    }

    out_re[site * NSC + i] = acc_re;
    out_im[site * NSC + i] = acc_im;
}

extern "C" void kernel_launch(void* const* d_in, const int* in_sizes, int n_in,
                              void* d_out, int out_size, void* d_ws, size_t ws_size,
                              hipStream_t stream) {
    const float* psi_re = (const float*)d_in[0];
    const float* psi_im = (const float*)d_in[1];
    const float* Kf_re  = (const float*)d_in[2];
    const float* Kf_im  = (const float*)d_in[3];
    const float* Kb_re  = (const float*)d_in[4];
    const float* Kb_im  = (const float*)d_in[5];

    float* out_re = (float*)d_out;
    float* out_im = (float*)d_out + (size_t)VOL * NSC;

    const int grid = VOL / SPB;   // 4096 blocks

    dslash_kernel<<<grid, THREADS, 0, stream>>>(psi_re, psi_im,
                                                Kf_re, Kf_im, Kb_re, Kb_im,
                                                out_re, out_im);
}

// Round 4
// 113.684 us; speedup vs baseline: 1.1076x; 1.0092x over previous
//
#include <hip/hip_runtime.h>

#define VOL   65536
#define NSC   12
#define DIAG  4.1f
#define SPB   16                  // sites per block = one full x-line
#define THREADS 192               // 3 waves
#define MATF  (SPB * 144)         // 2304 floats: one 16-site matrix array
#define STGF  (2 * MATF)          // 4608 floats per stage (re + im)
#define PSI_LINE 192              // floats per line per (re|im)
#define PSI_F (7 * 2 * PSI_LINE)  // 2688 floats staged psi

#define CMADD(kr, ki, vr, vi)                                              \
    sr += kr.x * vr.x - ki.x * vi.x;  si += kr.x * vi.x + ki.x * vr.x;     \
    sr += kr.y * vr.y - ki.y * vi.y;  si += kr.y * vi.y + ki.y * vr.y;     \
    sr += kr.z * vr.z - ki.z * vi.z;  si += kr.z * vi.z + ki.z * vr.z;     \
    sr += kr.w * vr.w - ki.w * vi.w;  si += kr.w * vi.w + ki.w * vr.w;

__device__ __forceinline__ void g2lds16(const float* g, float* l) {
    __builtin_amdgcn_global_load_lds(
        (const __attribute__((address_space(1))) unsigned int*)g,
        (__attribute__((address_space(3))) unsigned int*)l,
        16, 0, 0);
}

// issue the 6 staging loads (2 matrices x 3 chunks) for phase P into kb
template<int P>
__device__ __forceinline__ void stage(const float* Kf_re, const float* Kf_im,
                                      const float* Kb_re, const float* Kb_im,
                                      int site0, int w, int l, float* kb) {
    constexpr int mu = P >> 1;
    const float* re = (P & 1) ? Kb_re : Kf_re;
    const float* im = (P & 1) ? Kb_im : Kf_im;
    const size_t gb = ((size_t)mu * VOL + (size_t)site0) * 144;
    #pragma unroll
    for (int jj = 0; jj < 3; ++jj) {
        const int c = jj * 3 + w;                       // chunk 0..8, wave-uniform
        g2lds16(re + gb + c * 256 + l * 4, kb + 0 * MATF + c * 256 + l * 4);
        g2lds16(im + gb + c * 256 + l * 4, kb + 1 * MATF + c * 256 + l * 4);
    }
}

// pure-LDS compute for phase P: one complex row-dot, accumulate
template<int P>
__device__ __forceinline__ void phase_compute(const float* kb, const float* pb,
                                              int sl, int j,
                                              float& acc_re, float& acc_im) {
    constexpr int mu = P >> 1;
    constexpr int d  = P & 1;                 // 0 = fwd (+1), 1 = bwd (-1)
    constexpr int line = (mu < 3) ? (1 + mu * 2 + d) : 0;
    const int sidx = (mu < 3) ? sl : (d == 0 ? (sl + 1) & 15 : (sl + 15) & 15);

    const float4* kr = (const float4*)(kb + j * 12);
    const float4* ki = (const float4*)(kb + MATF + j * 12);
    const float4* vr = (const float4*)(pb + (line * 2 + 0) * PSI_LINE + sidx * 12);
    const float4* vi = (const float4*)(pb + (line * 2 + 1) * PSI_LINE + sidx * 12);

    float sr = 0.f, si = 0.f;
    #pragma unroll
    for (int q = 0; q < 3; ++q) {
        const float4 a = kr[q], b = ki[q];
        const float4 x = vr[q], y4 = vi[q];
        CMADD(a, b, x, y4);
    }
    acc_re -= 0.5f * sr;
    acc_im -= 0.5f * si;
}

#define WAITV(n) asm volatile("s_waitcnt vmcnt(" #n ")" ::: "memory")
#define CFENCE() asm volatile("" ::: "memory")

__global__ __launch_bounds__(THREADS) void dslash_kernel(
    const float* __restrict__ psi_re, const float* __restrict__ psi_im,
    const float* __restrict__ Kf_re,  const float* __restrict__ Kf_im,
    const float* __restrict__ Kb_re,  const float* __restrict__ Kb_im,
    float* __restrict__ out_re,       float* __restrict__ out_im)
{
    __shared__ float kbuf[2][STGF];   // 36.9 KB K double-buffer
    __shared__ float pbuf[PSI_F];     // 10.75 KB psi lines

    const int j  = threadIdx.x;       // 0..191
    const int w  = j >> 6;            // wave 0..2
    const int l  = j & 63;            // lane
    const int sl = j / NSC;           // local site == x (block is an x-line)
    const int lid = blockIdx.x;       // (t*16+z)*16+y
    const int site0 = lid * SPB;

    const int y = lid & 15, z = (lid >> 4) & 15, t = (lid >> 8) & 15;

    // global float-index base of each psi line (x-line = 192 floats)
    int lb[7];
    lb[0] = lid * 192;                                              // own
    lb[1] = ((((t + 1)  & 15) << 8) | (z << 4) | y) * 192;          // t+
    lb[2] = ((((t + 15) & 15) << 8) | (z << 4) | y) * 192;          // t-
    lb[3] = ((t << 8) | (((z + 1)  & 15) << 4) | y) * 192;          // z+
    lb[4] = ((t << 8) | (((z + 15) & 15) << 4) | y) * 192;          // z-
    lb[5] = ((t << 8) | (z << 4) | ((y + 1)  & 15)) * 192;          // y+
    lb[6] = ((t << 8) | (z << 4) | ((y + 15) & 15)) * 192;          // y-

    // ---- prologue: stage 7 psi lines (re+im) into LDS ----
    #pragma unroll
    for (int r = 0; r < 4; ++r) {
        const int idx = j + r * THREADS;          // 0..767, need 672
        if (idx < 672) {
            const int c  = idx % 48;              // float4 within line-array
            const int la = idx / 48;              // 0..13
            const int ar = la & 1, ln = la >> 1;
            const float4 v = *(const float4*)((ar ? psi_im : psi_re) + lb[ln] + c * 4);
            *(float4*)&pbuf[(ln * 2 + ar) * PSI_LINE + c * 4] = v;
        }
    }
    __syncthreads();   // psi staged; also drains prologue VMEM -> clean vmcnt ledger

    // diag term from own line
    float acc_re = DIAG * pbuf[0 * PSI_LINE + j];   // (line0,re)[sl*12+i] == [j]
    float acc_im = DIAG * pbuf[1 * PSI_LINE + j];

    // ---- pipeline prologue: stage phases 0,1 ----
    stage<0>(Kf_re, Kf_im, Kb_re, Kb_im, site0, w, l, kbuf[0]);
    stage<1>(Kf_re, Kf_im, Kb_re, Kb_im, site0, w, l, kbuf[1]);

    // ---- 8 phases: wait(counted) / bar / compute(LDS-only) / bar / issue p+2 ----
#define DO_PHASE(P, NWAIT)                                                    \
    WAITV(NWAIT);                                                             \
    __builtin_amdgcn_s_barrier();                                             \
    CFENCE();                                                                 \
    phase_compute<P>(kbuf[(P) & 1], pbuf, sl, j, acc_re, acc_im);             \
    CFENCE();                                                                 \
    __builtin_amdgcn_s_barrier();                                             \
    CFENCE();

    DO_PHASE(0, 6)
    stage<2>(Kf_re, Kf_im, Kb_re, Kb_im, site0, w, l, kbuf[0]);
    DO_PHASE(1, 6)
    stage<3>(Kf_re, Kf_im, Kb_re, Kb_im, site0, w, l, kbuf[1]);
    DO_PHASE(2, 6)
    stage<4>(Kf_re, Kf_im, Kb_re, Kb_im, site0, w, l, kbuf[0]);
    DO_PHASE(3, 6)
    stage<5>(Kf_re, Kf_im, Kb_re, Kb_im, site0, w, l, kbuf[1]);
    DO_PHASE(4, 6)
    stage<6>(Kf_re, Kf_im, Kb_re, Kb_im, site0, w, l, kbuf[0]);
    DO_PHASE(5, 6)
    stage<7>(Kf_re, Kf_im, Kb_re, Kb_im, site0, w, l, kbuf[1]);
    DO_PHASE(6, 6)
    DO_PHASE(7, 0)

    // ---- epilogue: coalesced stores (site0*12 + j) ----
    out_re[site0 * NSC + j] = acc_re;
    out_im[site0 * NSC + j] = acc_im;
}

extern "C" void kernel_launch(void* const* d_in, const int* in_sizes, int n_in,
                              void* d_out, int out_size, void* d_ws, size_t ws_size,
                              hipStream_t stream) {
    const float* psi_re = (const float*)d_in[0];
    const float* psi_im = (const float*)d_in[1];
    const float* Kf_re  = (const float*)d_in[2];
    const float* Kf_im  = (const float*)d_in[3];
    const float* Kb_re  = (const float*)d_in[4];
    const float* Kb_im  = (const float*)d_in[5];

    float* out_re = (float*)d_out;
    float* out_im = (float*)d_out + (size_t)VOL * NSC;

    dslash_kernel<<<VOL / SPB, THREADS, 0, stream>>>(psi_re, psi_im,
                                                     Kf_re, Kf_im, Kb_re, Kb_im,
                                                     out_re, out_im);
}

// Round 6
// 113.619 us; speedup vs baseline: 1.1083x; 1.0006x over previous
//
#include <hip/hip_runtime.h>

#define VOL   65536
#define NSC   12
#define DIAG  4.1f
#define SPB   16                  // sites per block = one x-line
#define THREADS 192               // 3 waves; wave w owns rows 4w..4w+3 of all 16 sites
#define KWF   1536                // floats per wave K phase-buffer: 2(re,im) x 16 sites x 48
#define PQ(line, ar, q) (((line)*2 + (ar))*3 + (q))   // pbuf float4-group index

#define CMADD(kr, ki, vr, vi)                                              \
    sr += kr.x * vr.x - ki.x * vi.x;  si += kr.x * vi.x + ki.x * vr.x;     \
    sr += kr.y * vr.y - ki.y * vi.y;  si += kr.y * vi.y + ki.y * vr.y;     \
    sr += kr.z * vr.z - ki.z * vi.z;  si += kr.z * vi.z + ki.z * vr.z;     \
    sr += kr.w * vr.w - ki.w * vi.w;  si += kr.w * vi.w + ki.w * vr.w;

__device__ __forceinline__ void g2lds16(const float* g, float* l) {
    __builtin_amdgcn_global_load_lds(
        (const __attribute__((address_space(1))) unsigned int*)g,
        (__attribute__((address_space(3))) unsigned int*)l,
        16, 0, 0);
}

#define WAITV(n) asm volatile("s_waitcnt vmcnt(" #n ")" ::: "memory")
#define WAITL()  asm volatile("s_waitcnt lgkmcnt(0)" ::: "memory")
#define SBAR()   __builtin_amdgcn_sched_barrier(0)

// Stage this wave's row-group (rows 4w..4w+3) of 16 sites for phase P into kwb.
// Per-lane GLOBAL addresses (allowed); LDS dest is lane-linear (required).
template<int P>
__device__ __forceinline__ void stageK(const float* __restrict__ Kf_re,
                                       const float* __restrict__ Kf_im,
                                       const float* __restrict__ Kb_re,
                                       const float* __restrict__ Kb_im,
                                       int site0, int w, int l,
                                       const int* goff, float* kwb) {
    constexpr int mu = P >> 1;
    const float* re = (P & 1) ? Kb_re : Kf_re;
    const float* im = (P & 1) ? Kb_im : Kf_im;
    // float4 units: matrix base (mu,site0) + this wave's row-group offset
    const size_t gb = ((size_t)(mu * VOL) + (size_t)site0) * 36 + (size_t)w * 12;
    #pragma unroll
    for (int jj = 0; jj < 3; ++jj) {
        const size_t g4 = gb + (size_t)goff[jj];   // goff = s*36 + f for c=jj*64+l
        g2lds16(re + 4 * g4, kwb + 0 * 768 + jj * 256 + l * 4);
        g2lds16(im + 4 * g4, kwb + 1 * 768 + jj * 256 + l * 4);
    }
}

// Pure-LDS compute for phase P: lane (s = l>>2, r = l&3) does the complex
// row-dot of K row (4w+r) with the neighbor psi vector of site s.
template<int P>
__device__ __forceinline__ void phase_compute(const float* __restrict__ kwb,
                                              const float* __restrict__ pbuf,
                                              int s, int r,
                                              float& acc_re, float& acc_im) {
    constexpr int mu = P >> 1;
    constexpr int d  = P & 1;                       // 0 = fwd(+1), 1 = bwd(-1)
    constexpr int line = (mu < 3) ? (1 + mu * 2 + d) : 0;
    const int sidx = (mu < 3) ? s : (d == 0 ? (s + 1) & 15 : (s + 15) & 15);

    const float4* k4 = (const float4*)kwb;
    const float4* p4 = (const float4*)pbuf;
    const int kb = s * 12 + r * 3;                  // float4 idx of this lane's row

    float sr = 0.f, si = 0.f;
    #pragma unroll
    for (int q = 0; q < 3; ++q) {
        const float4 a = k4[kb + q];                // K re
        const float4 b = k4[192 + kb + q];          // K im
        const float4 x = p4[PQ(line, 0, q) * 16 + sidx];   // psi re (broadcast x4)
        const float4 y4 = p4[PQ(line, 1, q) * 16 + sidx];  // psi im
        CMADD(a, b, x, y4);
    }
    acc_re -= 0.5f * sr;
    acc_im -= 0.5f * si;
}

__global__ __launch_bounds__(THREADS) void dslash_kernel(
    const float* __restrict__ psi_re, const float* __restrict__ psi_im,
    const float* __restrict__ Kf_re,  const float* __restrict__ Kf_im,
    const float* __restrict__ Kb_re,  const float* __restrict__ Kb_im,
    float* __restrict__ out_re,       float* __restrict__ out_im)
{
    __shared__ float kbuf[3][2][KWF];   // 36.9 KB: per-wave double-buffered K
    __shared__ float pbuf[672 * 4];     // 10.5 KB: psi [line][ar][q][site] float4s

    const int j  = threadIdx.x;
    const int w  = j >> 6;              // wave 0..2 -> rows 4w..4w+3
    const int l  = j & 63;
    const int s  = l >> 2;              // site 0..15
    const int r  = l & 3;               // row within row-group
    const int lid = blockIdx.x;         // (t*16+z)*16+y
    const int site0 = lid * SPB;
    const int y = lid & 15, z = (lid >> 4) & 15, t = (lid >> 8) & 15;

    // per-lane staging map: slot c = jj*64+l  ->  (site = c/12, f = c%12)
    int goff[3];
    #pragma unroll
    for (int jj = 0; jj < 3; ++jj) {
        const int c = jj * 64 + l;
        const int ss = c / 12;
        goff[jj] = ss * 36 + (c - ss * 12);
    }

    // global float base of each psi x-line (192 floats per line per re|im)
    int lb[7];
    lb[0] = lid * 192;
    lb[1] = ((((t + 1)  & 15) << 8) | (z << 4) | y) * 192;   // t+
    lb[2] = ((((t + 15) & 15) << 8) | (z << 4) | y) * 192;   // t-
    lb[3] = ((t << 8) | (((z + 1)  & 15) << 4) | y) * 192;   // z+
    lb[4] = ((t << 8) | (((z + 15) & 15) << 4) | y) * 192;   // z-
    lb[5] = ((t << 8) | (z << 4) | ((y + 1)  & 15)) * 192;   // y+
    lb[6] = ((t << 8) | (z << 4) | ((y + 15) & 15)) * 192;   // y-

    // ---- psi prologue: 7 lines x {re,im} -> pbuf, [q][site]-transposed ----
    #pragma unroll
    for (int rr = 0; rr < 4; ++rr) {
        const int idx = j + rr * THREADS;          // need 672 = 7*2*48
        if (idx < 672) {
            const int c  = idx % 48;               // float4 within (line,ar)
            const int la = idx / 48;
            const int ar = la & 1, ln = la >> 1;
            const float4 v = *(const float4*)((ar ? psi_im : psi_re) + lb[ln] + c * 4);
            const int q = c % 3, st = c / 3;
            *(float4*)&pbuf[(PQ(ln, ar, q) * 16 + st) * 4] = v;
        }
    }
    SBAR();   // keep stage issues strictly after psi loads/writes (clean vmcnt ledger)

    float* kwb0 = &kbuf[w][0][0];
    float* kwb1 = &kbuf[w][1][0];
    stageK<0>(Kf_re, Kf_im, Kb_re, Kb_im, site0, w, l, goff, kwb0);
    stageK<1>(Kf_re, Kf_im, Kb_re, Kb_im, site0, w, l, goff, kwb1);
    SBAR();
    WAITL();                               // psi ds_writes done (lgkm only)
    __builtin_amdgcn_s_barrier();          // the ONLY barrier: pbuf ready

    // diag term: psi_own(site s, element 4w+r) is at pbuf float idx PQ(0,ar,w)*64 + l
    float acc_re = DIAG * pbuf[PQ(0, 0, w) * 64 + l];
    float acc_im = DIAG * pbuf[PQ(0, 1, w) * 64 + l];

    // ---- 8 phases, barrier-free, per-wave counted vmcnt ----
#define PHASE(P, NW)                                                          \
    WAITV(NW);                                                                \
    SBAR();                                                                   \
    phase_compute<P>(((P) & 1) ? kwb1 : kwb0, pbuf, s, r, acc_re, acc_im);    \
    WAITL();   /* own ds_reads drained before DMA overwrite of this buffer */ \
    SBAR();

    PHASE(0, 6) stageK<2>(Kf_re, Kf_im, Kb_re, Kb_im, site0, w, l, goff, kwb0);
    PHASE(1, 6) stageK<3>(Kf_re, Kf_im, Kb_re, Kb_im, site0, w, l, goff, kwb1);
    PHASE(2, 6) stageK<4>(Kf_re, Kf_im, Kb_re, Kb_im, site0, w, l, goff, kwb0);
    PHASE(3, 6) stageK<5>(Kf_re, Kf_im, Kb_re, Kb_im, site0, w, l, goff, kwb1);
    PHASE(4, 6) stageK<6>(Kf_re, Kf_im, Kb_re, Kb_im, site0, w, l, goff, kwb0);
    PHASE(5, 6) stageK<7>(Kf_re, Kf_im, Kb_re, Kb_im, site0, w, l, goff, kwb1);
    PHASE(6, 6)
    PHASE(7, 0)

    // lane holds output element (site0+s, row 4w+r)
    const int o = (site0 + s) * NSC + 4 * w + r;
    out_re[o] = acc_re;
    out_im[o] = acc_im;
}

extern "C" void kernel_launch(void* const* d_in, const int* in_sizes, int n_in,
                              void* d_out, int out_size, void* d_ws, size_t ws_size,
                              hipStream_t stream) {
    const float* psi_re = (const float*)d_in[0];
    const float* psi_im = (const float*)d_in[1];
    const float* Kf_re  = (const float*)d_in[2];
    const float* Kf_im  = (const float*)d_in[3];
    const float* Kb_re  = (const float*)d_in[4];
    const float* Kb_im  = (const float*)d_in[5];

    float* out_re = (float*)d_out;
    float* out_im = (float*)d_out + (size_t)VOL * NSC;

    dslash_kernel<<<VOL / SPB, THREADS, 0, stream>>>(psi_re, psi_im,
                                                     Kf_re, Kf_im, Kb_re, Kb_im,
                                                     out_re, out_im);
}

// Round 7
// 113.037 us; speedup vs baseline: 1.1140x; 1.0052x over previous
//
#include <hip/hip_runtime.h>

#define VOL   65536
#define NSC   12
#define DIAG  4.1f
#define SPB   16                  // sites per block = one x-line
#define THREADS 192               // 3 waves; wave w owns rows 4w..4w+3 of all 16 sites
#define KWF   1536                // floats per wave K phase-buffer: 2(re,im) x 16 sites x 48
#define PSI_LINE 192              // floats per x-line per (re|im)

#define CMADD(kr, ki, vr, vi)                                              \
    sr += kr.x * vr.x - ki.x * vi.x;  si += kr.x * vi.x + ki.x * vr.x;     \
    sr += kr.y * vr.y - ki.y * vi.y;  si += kr.y * vi.y + ki.y * vr.y;     \
    sr += kr.z * vr.z - ki.z * vi.z;  si += kr.z * vi.z + ki.z * vr.z;     \
    sr += kr.w * vr.w - ki.w * vi.w;  si += kr.w * vi.w + ki.w * vr.w;

__device__ __forceinline__ void g2lds16(const float* g, float* l) {
    __builtin_amdgcn_global_load_lds(
        (const __attribute__((address_space(1))) unsigned int*)g,
        (__attribute__((address_space(3))) unsigned int*)l,
        16, 0, 0);
}

#define WAITV(n) asm volatile("s_waitcnt vmcnt(" #n ")" ::: "memory")
#define WAITL()  asm volatile("s_waitcnt lgkmcnt(0)" ::: "memory")
#define SBAR()   __builtin_amdgcn_sched_barrier(0)

// Stage this wave's row-group (rows 4w..4w+3) of 16 sites for phase P into kwb.
template<int P>
__device__ __forceinline__ void stageK(const float* __restrict__ Kf_re,
                                       const float* __restrict__ Kf_im,
                                       const float* __restrict__ Kb_re,
                                       const float* __restrict__ Kb_im,
                                       int site0, int w, int l,
                                       const int* goff, float* kwb) {
    constexpr int mu = P >> 1;
    const float* re = (P & 1) ? Kb_re : Kf_re;
    const float* im = (P & 1) ? Kb_im : Kf_im;
    const size_t gb = ((size_t)(mu * VOL) + (size_t)site0) * 36 + (size_t)w * 12;
    #pragma unroll
    for (int jj = 0; jj < 3; ++jj) {
        const size_t g4 = gb + (size_t)goff[jj];   // goff = s*36 + f for c=jj*64+l
        g2lds16(re + 4 * g4, kwb + 0 * 768 + jj * 256 + l * 4);
        g2lds16(im + 4 * g4, kwb + 1 * 768 + jj * 256 + l * 4);
    }
}

// Pure-LDS compute for phase P: lane (s = l>>2, r = l&3) does the complex
// row-dot of K row (4w+r) with the neighbor psi vector of site s.
// psi layout (R3-style, linear): pbuf[(line*2+ar)*PSI_LINE + site*12 + f]
template<int P>
__device__ __forceinline__ void phase_compute(const float* __restrict__ kwb,
                                              const float* __restrict__ pbuf,
                                              int s, int r,
                                              float& acc_re, float& acc_im) {
    constexpr int mu = P >> 1;
    constexpr int d  = P & 1;                       // 0 = fwd(+1), 1 = bwd(-1)
    constexpr int line = (mu < 3) ? (1 + mu * 2 + d) : 0;
    const int sidx = (mu < 3) ? s : (d == 0 ? (s + 1) & 15 : (s + 15) & 15);

    const float4* k4 = (const float4*)kwb;
    const int kb = s * 12 + r * 3;                  // float4 idx of this lane's row
    const float4* vr = (const float4*)(pbuf + (line * 2 + 0) * PSI_LINE + sidx * 12);
    const float4* vi = (const float4*)(pbuf + (line * 2 + 1) * PSI_LINE + sidx * 12);

    float sr = 0.f, si = 0.f;
    #pragma unroll
    for (int q = 0; q < 3; ++q) {
        const float4 a = k4[kb + q];                // K re
        const float4 b = k4[192 + kb + q];          // K im
        const float4 x = vr[q];                     // psi re
        const float4 y4 = vi[q];                    // psi im
        CMADD(a, b, x, y4);
    }
    acc_re -= 0.5f * sr;
    acc_im -= 0.5f * si;
}

__global__ __launch_bounds__(THREADS) void dslash_kernel(
    const float* __restrict__ psi_re, const float* __restrict__ psi_im,
    const float* __restrict__ Kf_re,  const float* __restrict__ Kf_im,
    const float* __restrict__ Kb_re,  const float* __restrict__ Kb_im,
    float* __restrict__ out_re,       float* __restrict__ out_im)
{
    __shared__ float kbuf[3][2][KWF];   // 36.9 KB: per-wave double-buffered K
    __shared__ float pbuf[7 * 2 * PSI_LINE];   // 10.5 KB psi, linear layout

    const int j  = threadIdx.x;
    const int w  = j >> 6;              // wave 0..2 -> rows 4w..4w+3
    const int l  = j & 63;
    const int s  = l >> 2;              // site 0..15
    const int r  = l & 3;               // row within row-group
    const int lid = blockIdx.x;         // (t*16+z)*16+y
    const int site0 = lid * SPB;
    const int y = lid & 15, z = (lid >> 4) & 15, t = (lid >> 8) & 15;

    // per-lane staging map: slot c = jj*64+l  ->  (site = c/12, f = c%12)
    int goff[3];
    #pragma unroll
    for (int jj = 0; jj < 3; ++jj) {
        const int c = jj * 64 + l;
        const int ss = c / 12;
        goff[jj] = ss * 36 + (c - ss * 12);
    }

    // global float base of each psi x-line (192 floats per line per re|im)
    int lb[7];
    lb[0] = lid * 192;
    lb[1] = ((((t + 1)  & 15) << 8) | (z << 4) | y) * 192;   // t+
    lb[2] = ((((t + 15) & 15) << 8) | (z << 4) | y) * 192;   // t-
    lb[3] = ((t << 8) | (((z + 1)  & 15) << 4) | y) * 192;   // z+
    lb[4] = ((t << 8) | (((z + 15) & 15) << 4) | y) * 192;   // z-
    lb[5] = ((t << 8) | (z << 4) | ((y + 1)  & 15)) * 192;   // y+
    lb[6] = ((t << 8) | (z << 4) | ((y + 15) & 15)) * 192;   // y-

    // ---- psi prologue: linear copy, contiguous float4 per lane (R3 layout) ----
    #pragma unroll
    for (int rr = 0; rr < 4; ++rr) {
        const int idx = j + rr * THREADS;          // need 672 = 7*2*48
        if (idx < 672) {
            const int c  = idx % 48;               // float4 within (line,ar)
            const int la = idx / 48;
            const int ar = la & 1, ln = la >> 1;
            const float4 v = *(const float4*)((ar ? psi_im : psi_re) + lb[ln] + c * 4);
            *(float4*)&pbuf[(ln * 2 + ar) * PSI_LINE + c * 4] = v;
        }
    }
    SBAR();   // keep stage issues strictly after psi loads/writes (clean vmcnt ledger)

    float* kwb0 = &kbuf[w][0][0];
    float* kwb1 = &kbuf[w][1][0];
    stageK<0>(Kf_re, Kf_im, Kb_re, Kb_im, site0, w, l, goff, kwb0);
    stageK<1>(Kf_re, Kf_im, Kb_re, Kb_im, site0, w, l, goff, kwb1);
    SBAR();
    WAITL();                               // psi ds_writes done
    __builtin_amdgcn_s_barrier();          // the ONLY barrier: pbuf ready

    // diag term: lane owns element (site s, row 4w+r) = pbuf[...+ s*12 + 4w + r]
    float acc_re = DIAG * pbuf[0 * PSI_LINE + s * 12 + 4 * w + r];
    float acc_im = DIAG * pbuf[1 * PSI_LINE + s * 12 + 4 * w + r];

    // ---- 8 phases, barrier-free, per-wave counted vmcnt ----
#define PHASE(P, NW)                                                          \
    WAITV(NW);                                                                \
    SBAR();                                                                   \
    phase_compute<P>(((P) & 1) ? kwb1 : kwb0, pbuf, s, r, acc_re, acc_im);    \
    WAITL();   /* own ds_reads drained before DMA overwrite of this buffer */ \
    SBAR();

    PHASE(0, 6) stageK<2>(Kf_re, Kf_im, Kb_re, Kb_im, site0, w, l, goff, kwb0);
    PHASE(1, 6) stageK<3>(Kf_re, Kf_im, Kb_re, Kb_im, site0, w, l, goff, kwb1);
    PHASE(2, 6) stageK<4>(Kf_re, Kf_im, Kb_re, Kb_im, site0, w, l, goff, kwb0);
    PHASE(3, 6) stageK<5>(Kf_re, Kf_im, Kb_re, Kb_im, site0, w, l, goff, kwb1);
    PHASE(4, 6) stageK<6>(Kf_re, Kf_im, Kb_re, Kb_im, site0, w, l, goff, kwb0);
    PHASE(5, 6) stageK<7>(Kf_re, Kf_im, Kb_re, Kb_im, site0, w, l, goff, kwb1);
    PHASE(6, 6)
    PHASE(7, 0)

    // lane holds output element (site0+s, row 4w+r)
    const int o = (site0 + s) * NSC + 4 * w + r;
    out_re[o] = acc_re;
    out_im[o] = acc_im;
}

extern "C" void kernel_launch(void* const* d_in, const int* in_sizes, int n_in,
                              void* d_out, int out_size, void* d_ws, size_t ws_size,
                              hipStream_t stream) {
    const float* psi_re = (const float*)d_in[0];
    const float* psi_im = (const float*)d_in[1];
    const float* Kf_re  = (const float*)d_in[2];
    const float* Kf_im  = (const float*)d_in[3];
    const float* Kb_re  = (const float*)d_in[4];
    const float* Kb_im  = (const float*)d_in[5];

    float* out_re = (float*)d_out;
    float* out_im = (float*)d_out + (size_t)VOL * NSC;

    dslash_kernel<<<VOL / SPB, THREADS, 0, stream>>>(psi_re, psi_im,
                                                     Kf_re, Kf_im, Kb_re, Kb_im,
                                                     out_re, out_im);
}